// Round 10
// baseline (81.484 us; speedup 1.0000x reference)
//
#include <hip/hip_runtime.h>
#include <math.h>

// DetectionLayer: x(32,255,76,76) f32 -> out(32,17328,85) f32
// Block (512 thr) = (b, row i); processes BOTH j-halves, software-pipelined:
//   load0 -> xform0->LDS -> load1(issued early) -> SOFTBAR -> dump0
//   -> SOFTBAR -> xform1->LDS -> SOFTBAR -> dump1
// SOFTBAR = s_waitcnt lgkmcnt(0) + s_barrier (NO vmcnt drain): orders LDS
// across waves while global loads/stores stay in flight across the barrier
// (__syncthreads would drain vmcnt(0) and serialize the memory pipeline).
// Half-1 load latency hides under dump0; dump0 stores drain under xform1.
// LDS 40800B (one half, reused) -> 4 blocks/CU x 8 waves = 32 waves/CU.
// Corners (t<4, 12/255 channels) finalized inline via cache-warm partner
// channel loads; a = c/85 exact. Dump = contiguous float4, 16B-aligned.
// XCD swizzle: logical (b,i) chunked; 2432%8==0 -> bijective.

#define NCH    255
#define NATTR  85
#define HW     5776
#define GW     76
#define NBATCH 32
#define BLOCK  512
#define NWG    (NBATCH * GW)       // 2432
#define CHUNK  (NWG / 8)           // 304
#define NIT    5

#define SOFT_BAR() asm volatile("s_waitcnt lgkmcnt(0)\n\ts_barrier" ::: "memory")

__device__ __forceinline__ float sigm(float x) {
    return __builtin_amdgcn_rcpf(1.0f + __expf(-x));
}

template<int NQ>   // float4 units per channel: 10 (half 0) or 9 (half 1)
__device__ __forceinline__ void load_half(const float* __restrict__ src,
                                          float4* __restrict__ xv) {
    constexpr int NU = NCH * NQ;
    #pragma unroll
    for (int k = 0; k < NIT; ++k) {
        int e = threadIdx.x + BLOCK * k;
        if (e < NU) {
            int c = e / NQ, q = e - c * NQ;
            xv[k] = *(const float4*)(src + (size_t)c * HW + 4 * q);
        }
    }
}

template<int NQ>
__device__ __forceinline__ void xform_half(const float* __restrict__ src,
                                           float* __restrict__ lds,
                                           const float4* __restrict__ xv,
                                           int jg0, float fi) {
    constexpr int NU = NCH * NQ;
    #pragma unroll
    for (int k = 0; k < NIT; ++k) {
        int e = threadIdx.x + BLOCK * k;
        if (e < NU) {
            int c = e / NQ, q = e - c * NQ;
            int a = c / 85;              // exact
            int t = c - 85 * a;
            float4 v = xv[k];
            float r0, r1, r2, r3;
            if (t >= 4) {
                r0 = sigm(v.x); r1 = sigm(v.y); r2 = sigm(v.z); r3 = sigm(v.w);
            } else {
                int cp = (t < 2) ? c + 2 : c - 2;      // partner channel
                float4 pv = *(const float4*)(src + (size_t)cp * HW + 4 * q);
                float ancw = (a == 0) ? 10.f : (a == 1) ? 16.f : 33.f;
                float anch = (a == 0) ? 13.f : (a == 1) ? 30.f : 23.f;
                float anc  = ((t & 1) ? anch : ancw) * (0.5f / 608.f);
                float vv[4] = {v.x, v.y, v.z, v.w};
                float pp[4] = {pv.x, pv.y, pv.z, pv.w};
                float rr[4];
                #pragma unroll
                for (int m = 0; m < 4; ++m) {
                    float coord = (t & 1) ? fi : (float)(jg0 + 4 * q + m);
                    float sin_ = (t < 2) ? vv[m] : pp[m];
                    float ein_ = (t < 2) ? pp[m] : vv[m];
                    float ixy = (sigm(sin_) * 1.05f - 0.025f + coord) * (1.0f / 76.0f);
                    float wh2 = __expf(ein_) * anc;
                    rr[m] = (t < 2) ? (ixy - wh2) : (ixy + wh2);
                }
                r0 = rr[0]; r1 = rr[1]; r2 = rr[2]; r3 = rr[3];
            }
            float* lp = &lds[(4 * q) * NCH + c];
            lp[0]       = r0;
            lp[NCH]     = r1;
            lp[2 * NCH] = r2;
            lp[3 * NCH] = r3;
        }
    }
}

template<int NQ>
__device__ __forceinline__ void dump_half(float* __restrict__ dst,
                                          const float* __restrict__ lds) {
    constexpr int NU = NCH * NQ;
    float4* __restrict__ dv = (float4*)dst;
    const float4* lv = (const float4*)lds;
    #pragma unroll
    for (int k = 0; k < NIT; ++k) {
        int e = threadIdx.x + BLOCK * k;
        if (e < NU) dv[e] = lv[e];
    }
}

__global__ __launch_bounds__(BLOCK, 8) void det_kernel(const float* __restrict__ in,
                                                       float* __restrict__ out) {
    __shared__ float lds[NCH * 40];    // 40800 B -> 4 blocks/CU

    int hw = blockIdx.x;
    int L  = (hw & 7) * CHUNK + (hw >> 3);
    int i  = L % GW;
    int b  = L / GW;

    const float* __restrict__ src = in + (size_t)b * (NCH * HW) + (size_t)i * GW;
    float* __restrict__ dst = out + ((size_t)b * 17328 + (size_t)i * 228) * NATTR;
    const float fi = (float)i;

    float4 x0[NIT], x1[NIT];

    load_half<10>(src, x0);                    // half 0: cols [0,40)
    xform_half<10>(src, lds, x0, 0, fi);
    load_half<9>(src + 40, x1);                // half 1 loads issued EARLY
    SOFT_BAR();                                // LDS visible; vmem in flight
    dump_half<10>(dst, lds);
    SOFT_BAR();                                // dump0 ds_reads done
    xform_half<9>(src + 40, lds, x1, 40, fi);  // overlaps dump0 stores
    SOFT_BAR();
    dump_half<9>(dst + 40 * NCH, lds);
}

extern "C" void kernel_launch(void* const* d_in, const int* in_sizes, int n_in,
                              void* d_out, int out_size, void* d_ws, size_t ws_size,
                              hipStream_t stream) {
    const float* x = (const float*)d_in[0];
    float* out = (float*)d_out;
    det_kernel<<<NWG, BLOCK, 0, stream>>>(x, out);
}